// Round 1
// baseline (2968.583 us; speedup 1.0000x reference)
//
#include <hip/hip_runtime.h>

#define N_NODES 100000
#define N_EDGES 1600000
#define IN_F 64
#define HID 128
#define N_CLS 64

// ---------------- zero workspace ----------------
__global__ void k_zero(float4* __restrict__ p, int n4) {
    int i = blockIdx.x * blockDim.x + threadIdx.x;
    if (i < n4) p[i] = make_float4(0.f, 0.f, 0.f, 0.f);
}

// ---------------- init output with bias ----------------
__global__ void k_init_bias(float* __restrict__ out, const float* __restrict__ b2, int n) {
    int i = blockIdx.x * blockDim.x + threadIdx.x;
    if (i < n) out[i] = b2[i & 63];
}

// ---------------- edge scatter-sum: out[dst] += feat[src], 64 features ----------------
// 16 threads per edge, each handles a float4 chunk (features are 64 fp32 = 16 float4).
__global__ void k_scatter64(const float* __restrict__ feat,
                            const int* __restrict__ src,
                            const int* __restrict__ dst,
                            float* __restrict__ out) {
    int i = blockIdx.x * blockDim.x + threadIdx.x;   // 0 .. N_EDGES*16-1
    int e = i >> 4;
    if (e >= N_EDGES) return;
    int j = (i & 15) << 2;                            // feature offset 0,4,...,60
    int s = src[e];
    int d = dst[e];
    float4 v = *reinterpret_cast<const float4*>(feat + (size_t)s * 64 + j);
    float* o = out + (size_t)d * 64 + j;
    atomicAdd(o + 0, v.x);
    atomicAdd(o + 1, v.y);
    atomicAdd(o + 2, v.z);
    atomicAdd(o + 3, v.w);
}

// ---------------- fused MLP: Z = relu(A*W1 + b1) * W2, in-place A->Z ----------------
#define ROWS 16
__global__ __launch_bounds__(256) void k_mlp(float* __restrict__ A,
                                             const float* __restrict__ W1,
                                             const float* __restrict__ b1,
                                             const float* __restrict__ W2) {
    __shared__ float W1s[64 * 128];   // 32 KB
    __shared__ float W2s[128 * 64];   // 32 KB
    __shared__ float b1s[128];
    __shared__ float xs[ROWS * 64];   // 4 KB
    __shared__ float hs[ROWS * 128];  // 8 KB
    const int t = threadIdx.x;
    const int row0 = blockIdx.x * ROWS;

    for (int i = t; i < 64 * 128; i += 256) W1s[i] = W1[i];
    for (int i = t; i < 128 * 64; i += 256) W2s[i] = W2[i];
    if (t < 128) b1s[t] = b1[t];
    for (int i = t; i < ROWS * 64; i += 256) {
        int r = i >> 6;
        xs[i] = A[(size_t)(row0 + r) * 64 + (i & 63)];
    }
    __syncthreads();

    // h = relu(x*W1 + b1): 16*128 = 2048 outputs, 8 per thread
    for (int it = 0; it < (ROWS * 128) / 256; ++it) {
        int idx = t + it * 256;
        int r = idx >> 7, c = idx & 127;
        float acc = b1s[c];
        const float* xr = xs + r * 64;
#pragma unroll
        for (int k = 0; k < 64; ++k) acc = fmaf(xr[k], W1s[k * 128 + c], acc);
        hs[idx] = fmaxf(acc, 0.f);
    }
    __syncthreads();

    // z = h*W2: 16*64 = 1024 outputs, 4 per thread; write back in place
    for (int it = 0; it < (ROWS * 64) / 256; ++it) {
        int idx = t + it * 256;
        int r = idx >> 6, c = idx & 63;
        float acc = 0.f;
        const float* hr = hs + r * 128;
#pragma unroll
        for (int k = 0; k < 128; ++k) acc = fmaf(hr[k], W2s[k * 64 + c], acc);
        A[(size_t)(row0 + r) * 64 + c] = acc;
    }
}

extern "C" void kernel_launch(void* const* d_in, const int* in_sizes, int n_in,
                              void* d_out, int out_size, void* d_ws, size_t ws_size,
                              hipStream_t stream) {
    const float* x  = (const float*)d_in[0];
    const float* W1 = (const float*)d_in[1];
    const float* b1 = (const float*)d_in[2];
    const float* W2 = (const float*)d_in[3];
    const float* b2 = (const float*)d_in[4];
    const int* src  = (const int*)d_in[5];
    const int* dst  = (const int*)d_in[6];
    float* out = (float*)d_out;

    float* A = (float*)d_ws;                        // [N_NODES, 64] agg1 then z (in-place)

    const int nfeat = N_NODES * 64;                 // 6,400,000
    const int nfeat4 = nfeat / 4;                   // 1,600,000

    // 1) zero agg buffer
    k_zero<<<(nfeat4 + 255) / 256, 256, 0, stream>>>((float4*)A, nfeat4);

    // 2) agg = scatter-sum of x over edges
    {
        int threads = N_EDGES * 16;
        k_scatter64<<<(threads + 255) / 256, 256, 0, stream>>>(x, src, dst, A);
    }

    // 3) A <- relu(A*W1+b1)*W2   (in-place)
    k_mlp<<<N_NODES / ROWS, 256, 0, stream>>>(A, W1, b1, W2);

    // 4) out = b2 broadcast
    k_init_bias<<<(nfeat + 255) / 256, 256, 0, stream>>>(out, b2, nfeat);

    // 5) out += scatter-sum of A over edges
    {
        int threads = N_EDGES * 16;
        k_scatter64<<<(threads + 255) / 256, 256, 0, stream>>>(A, src, dst, out);
    }
}

// Round 2
// 697.299 us; speedup vs baseline: 4.2573x; 4.2573x over previous
//
#include <hip/hip_runtime.h>

#define N_NODES 100000
#define N_EDGES 1600000
#define IN_F 64
#define HID 128
#define N_CLS 64

// ================= generic helpers =================
__global__ void k_zero_f4(float4* __restrict__ p, int n4) {
    int i = blockIdx.x * blockDim.x + threadIdx.x;
    if (i < n4) p[i] = make_float4(0.f, 0.f, 0.f, 0.f);
}
__global__ void k_zero_i(int* __restrict__ p, int n) {
    int i = blockIdx.x * blockDim.x + threadIdx.x;
    if (i < n) p[i] = 0;
}
__global__ void k_init_bias(float* __restrict__ out, const float* __restrict__ b2, int n) {
    int i = blockIdx.x * blockDim.x + threadIdx.x;
    if (i < n) out[i] = b2[i & 63];
}

// ================= CSR build =================
__global__ void k_hist(const int* __restrict__ dst, int* __restrict__ deg) {
    int e = blockIdx.x * blockDim.x + threadIdx.x;
    if (e < N_EDGES) atomicAdd(&deg[dst[e]], 1);
}

// single-block exclusive scan of deg[N_NODES] -> off[N_NODES], off[N_NODES]=N_EDGES
__global__ __launch_bounds__(1024) void k_scan(const int* __restrict__ deg, int* __restrict__ off) {
    __shared__ int buf[2][1024];
    const int t = threadIdx.x;
    const int CH = (N_NODES + 1023) / 1024;   // 98
    const int b = t * CH;
    int sum = 0;
    for (int i = 0; i < CH; ++i) {
        int idx = b + i;
        if (idx < N_NODES) sum += deg[idx];
    }
    buf[0][t] = sum;
    __syncthreads();
    int cur = 0;
    for (int d = 1; d < 1024; d <<= 1) {
        int v = buf[cur][t];
        if (t >= d) v += buf[cur][t - d];
        buf[cur ^ 1][t] = v;
        __syncthreads();
        cur ^= 1;
    }
    int run = buf[cur][t] - sum;              // exclusive prefix of this chunk
    for (int i = 0; i < CH; ++i) {
        int idx = b + i;
        if (idx < N_NODES) {
            off[idx] = run;
            run += deg[idx];
        }
    }
    if (t == 0) off[N_NODES] = N_EDGES;
}

__global__ void k_fill(const int* __restrict__ src, const int* __restrict__ dst,
                       const int* __restrict__ off, int* __restrict__ cursor,
                       int* __restrict__ es) {
    int e = blockIdx.x * blockDim.x + threadIdx.x;
    if (e >= N_EDGES) return;
    int d = dst[e];
    int pos = atomicAdd(&cursor[d], 1);
    es[off[d] + pos] = src[e];
}

// ================= gather aggregation: one wave per node =================
// out[n][lane] = (bias? bias[lane]:0) + sum_{e in CSR(n)} feat[es[e]][lane]
__global__ __launch_bounds__(256) void k_gather(const float* __restrict__ feat,
                                                const int* __restrict__ es,
                                                const int* __restrict__ off,
                                                const float* __restrict__ bias,
                                                float* __restrict__ out) {
    const int wave = threadIdx.x >> 6;
    const int lane = threadIdx.x & 63;
    const int n = blockIdx.x * 4 + wave;
    if (n >= N_NODES) return;
    const int beg = off[n], end = off[n + 1];
    float acc = bias ? bias[lane] : 0.f;
    for (int base = beg; base < end; base += 64) {
        int m = end - base; if (m > 64) m = 64;
        int id = (lane < m) ? es[base + lane] : 0;
        int k = 0;
        for (; k + 4 <= m; k += 4) {
            int s0 = __shfl(id, k), s1 = __shfl(id, k + 1);
            int s2 = __shfl(id, k + 2), s3 = __shfl(id, k + 3);
            float v0 = feat[(size_t)s0 * 64 + lane];
            float v1 = feat[(size_t)s1 * 64 + lane];
            float v2 = feat[(size_t)s2 * 64 + lane];
            float v3 = feat[(size_t)s3 * 64 + lane];
            acc += (v0 + v1) + (v2 + v3);
        }
        for (; k < m; ++k) {
            int s = __shfl(id, k);
            acc += feat[(size_t)s * 64 + lane];
        }
    }
    out[(size_t)n * 64 + lane] = acc;
}

// ================= fallback atomic scatter (if ws too small) =================
__global__ void k_scatter64(const float* __restrict__ feat,
                            const int* __restrict__ src,
                            const int* __restrict__ dst,
                            float* __restrict__ out) {
    int i = blockIdx.x * blockDim.x + threadIdx.x;
    int e = i >> 4;
    if (e >= N_EDGES) return;
    int j = (i & 15) << 2;
    int s = src[e];
    int d = dst[e];
    float4 v = *reinterpret_cast<const float4*>(feat + (size_t)s * 64 + j);
    float* o = out + (size_t)d * 64 + j;
    atomicAdd(o + 0, v.x);
    atomicAdd(o + 1, v.y);
    atomicAdd(o + 2, v.z);
    atomicAdd(o + 3, v.w);
}

// ================= fused MLP: Z = relu(A*W1 + b1) * W2, in-place =================
#define ROWS 16
__global__ __launch_bounds__(256) void k_mlp(float* __restrict__ A,
                                             const float* __restrict__ W1,
                                             const float* __restrict__ b1,
                                             const float* __restrict__ W2) {
    __shared__ float W1s[64 * 128];
    __shared__ float W2s[128 * 64];
    __shared__ float b1s[128];
    __shared__ float xs[ROWS * 64];
    __shared__ float hs[ROWS * 128];
    const int t = threadIdx.x;
    const int row0 = blockIdx.x * ROWS;

    for (int i = t; i < 64 * 128; i += 256) W1s[i] = W1[i];
    for (int i = t; i < 128 * 64; i += 256) W2s[i] = W2[i];
    if (t < 128) b1s[t] = b1[t];
    for (int i = t; i < ROWS * 64; i += 256) {
        int r = i >> 6;
        xs[i] = A[(size_t)(row0 + r) * 64 + (i & 63)];
    }
    __syncthreads();

    for (int it = 0; it < (ROWS * 128) / 256; ++it) {
        int idx = t + it * 256;
        int r = idx >> 7, c = idx & 127;
        float acc = b1s[c];
        const float* xr = xs + r * 64;
#pragma unroll
        for (int k = 0; k < 64; ++k) acc = fmaf(xr[k], W1s[k * 128 + c], acc);
        hs[idx] = fmaxf(acc, 0.f);
    }
    __syncthreads();

    for (int it = 0; it < (ROWS * 64) / 256; ++it) {
        int idx = t + it * 256;
        int r = idx >> 6, c = idx & 63;
        float acc = 0.f;
        const float* hr = hs + r * 128;
#pragma unroll
        for (int k = 0; k < 128; ++k) acc = fmaf(hr[k], W2s[k * 64 + c], acc);
        A[(size_t)(row0 + r) * 64 + c] = acc;
    }
}

extern "C" void kernel_launch(void* const* d_in, const int* in_sizes, int n_in,
                              void* d_out, int out_size, void* d_ws, size_t ws_size,
                              hipStream_t stream) {
    const float* x  = (const float*)d_in[0];
    const float* W1 = (const float*)d_in[1];
    const float* b1 = (const float*)d_in[2];
    const float* W2 = (const float*)d_in[3];
    const float* b2 = (const float*)d_in[4];
    const int* src  = (const int*)d_in[5];
    const int* dst  = (const int*)d_in[6];
    float* out = (float*)d_out;

    const int nfeat = N_NODES * 64;
    const int nfeat4 = nfeat / 4;

    // workspace layout
    char* ws = (char*)d_ws;
    float* A    = (float*)ws;                    ws += (size_t)nfeat * 4;          // 25.6 MB
    int* deg    = (int*)ws;                      ws += (size_t)N_NODES * 4;
    int* off    = (int*)ws;                      ws += (size_t)(N_NODES + 1) * 4;
    int* cursor = (int*)ws;                      ws += (size_t)N_NODES * 4;
    int* es     = (int*)ws;                      ws += (size_t)N_EDGES * 4;        // 6.4 MB
    size_t need = (size_t)(ws - (char*)d_ws);

    if (ws_size >= need) {
        // ---- CSR build ----
        k_zero_i<<<(N_NODES + 255) / 256, 256, 0, stream>>>(deg, N_NODES);
        k_hist<<<(N_EDGES + 255) / 256, 256, 0, stream>>>(dst, deg);
        k_scan<<<1, 1024, 0, stream>>>(deg, off);
        k_zero_i<<<(N_NODES + 255) / 256, 256, 0, stream>>>(cursor, N_NODES);
        k_fill<<<(N_EDGES + 255) / 256, 256, 0, stream>>>(src, dst, off, cursor, es);

        // ---- layer 1 aggregate: A = segsum(x) ----
        k_gather<<<(N_NODES + 3) / 4, 256, 0, stream>>>(x, es, off, nullptr, A);
        // ---- MLP in place: A = relu(A*W1+b1)*W2 ----
        k_mlp<<<N_NODES / ROWS, 256, 0, stream>>>(A, W1, b1, W2);
        // ---- layer 2 aggregate + bias: out = b2 + segsum(A) ----
        k_gather<<<(N_NODES + 3) / 4, 256, 0, stream>>>(A, es, off, b2, out);
    } else {
        // fallback: atomic scatter path (round-1)
        k_zero_f4<<<(nfeat4 + 255) / 256, 256, 0, stream>>>((float4*)A, nfeat4);
        int threads = N_EDGES * 16;
        k_scatter64<<<(threads + 255) / 256, 256, 0, stream>>>(x, src, dst, A);
        k_mlp<<<N_NODES / ROWS, 256, 0, stream>>>(A, W1, b1, W2);
        k_init_bias<<<(nfeat + 255) / 256, 256, 0, stream>>>(out, b2, nfeat);
        k_scatter64<<<(threads + 255) / 256, 256, 0, stream>>>(A, src, dst, out);
    }
}

// Round 3
// 530.070 us; speedup vs baseline: 5.6004x; 1.3155x over previous
//
#include <hip/hip_runtime.h>

#define N_NODES 100000
#define N_EDGES 1600000
#define IN_F 64
#define HID 128
#define N_CLS 64

// ================= generic helpers =================
__global__ void k_zero_f4(float4* __restrict__ p, int n4) {
    int i = blockIdx.x * blockDim.x + threadIdx.x;
    if (i < n4) p[i] = make_float4(0.f, 0.f, 0.f, 0.f);
}
__global__ void k_zero_i(int* __restrict__ p, int n) {
    int i = blockIdx.x * blockDim.x + threadIdx.x;
    if (i < n) p[i] = 0;
}
__global__ void k_init_bias(float* __restrict__ out, const float* __restrict__ b2, int n) {
    int i = blockIdx.x * blockDim.x + threadIdx.x;
    if (i < n) out[i] = b2[i & 63];
}

// ================= CSR build =================
__global__ void k_hist(const int* __restrict__ dst, int* __restrict__ deg) {
    int e = blockIdx.x * blockDim.x + threadIdx.x;
    if (e < N_EDGES) atomicAdd(&deg[dst[e]], 1);
}

__global__ __launch_bounds__(1024) void k_scan(const int* __restrict__ deg, int* __restrict__ off) {
    __shared__ int buf[2][1024];
    const int t = threadIdx.x;
    const int CH = (N_NODES + 1023) / 1024;   // 98
    const int b = t * CH;
    int sum = 0;
    for (int i = 0; i < CH; ++i) {
        int idx = b + i;
        if (idx < N_NODES) sum += deg[idx];
    }
    buf[0][t] = sum;
    __syncthreads();
    int cur = 0;
    for (int d = 1; d < 1024; d <<= 1) {
        int v = buf[cur][t];
        if (t >= d) v += buf[cur][t - d];
        buf[cur ^ 1][t] = v;
        __syncthreads();
        cur ^= 1;
    }
    int run = buf[cur][t] - sum;              // exclusive prefix of this chunk
    for (int i = 0; i < CH; ++i) {
        int idx = b + i;
        if (idx < N_NODES) {
            off[idx] = run;
            run += deg[idx];
        }
    }
    if (t == 0) off[N_NODES] = N_EDGES;
}

__global__ void k_fill(const int* __restrict__ src, const int* __restrict__ dst,
                       const int* __restrict__ off, int* __restrict__ cursor,
                       int* __restrict__ es) {
    int e = blockIdx.x * blockDim.x + threadIdx.x;
    if (e >= N_EDGES) return;
    int d = dst[e];
    int pos = atomicAdd(&cursor[d], 1);
    es[off[d] + pos] = src[e];
}

// ================= gather aggregation: one wave per node =================
__global__ __launch_bounds__(256) void k_gather(const float* __restrict__ feat,
                                                const int* __restrict__ es,
                                                const int* __restrict__ off,
                                                const float* __restrict__ bias,
                                                float* __restrict__ out) {
    const int wave = threadIdx.x >> 6;
    const int lane = threadIdx.x & 63;
    const int n = blockIdx.x * 4 + wave;
    if (n >= N_NODES) return;
    const int beg = off[n], end = off[n + 1];
    float acc = bias ? bias[lane] : 0.f;
    for (int base = beg; base < end; base += 64) {
        int m = end - base; if (m > 64) m = 64;
        int id = (lane < m) ? es[base + lane] : 0;
        int k = 0;
        for (; k + 4 <= m; k += 4) {
            int s0 = __shfl(id, k), s1 = __shfl(id, k + 1);
            int s2 = __shfl(id, k + 2), s3 = __shfl(id, k + 3);
            float v0 = feat[(size_t)s0 * 64 + lane];
            float v1 = feat[(size_t)s1 * 64 + lane];
            float v2 = feat[(size_t)s2 * 64 + lane];
            float v3 = feat[(size_t)s3 * 64 + lane];
            acc += (v0 + v1) + (v2 + v3);
        }
        for (; k < m; ++k) {
            int s = __shfl(id, k);
            acc += feat[(size_t)s * 64 + lane];
        }
    }
    out[(size_t)n * 64 + lane] = acc;
}

// ================= fallback atomic scatter (if ws too small) =================
__global__ void k_scatter64(const float* __restrict__ feat,
                            const int* __restrict__ src,
                            const int* __restrict__ dst,
                            float* __restrict__ out) {
    int i = blockIdx.x * blockDim.x + threadIdx.x;
    int e = i >> 4;
    if (e >= N_EDGES) return;
    int j = (i & 15) << 2;
    int s = src[e];
    int d = dst[e];
    float4 v = *reinterpret_cast<const float4*>(feat + (size_t)s * 64 + j);
    float* o = out + (size_t)d * 64 + j;
    atomicAdd(o + 0, v.x);
    atomicAdd(o + 1, v.y);
    atomicAdd(o + 2, v.z);
    atomicAdd(o + 3, v.w);
}

// ================= fused MLP: Z = relu(A*W1 + b1) * W2, in-place, register-tiled =================
#define MROWS 32
__global__ __launch_bounds__(256, 2) void k_mlp(float* __restrict__ A,
                                                const float* __restrict__ W1,
                                                const float* __restrict__ b1,
                                                const float* __restrict__ W2) {
    __shared__ float Ws[64 * 128];      // 32 KB: holds W1, then reused for W2
    __shared__ float xs[64 * 36];       // x transposed [k][row], padded stride 36
    __shared__ float hs[32 * 132];      // h row-major, padded stride 132
    __shared__ float b1s[128];
    const int t = threadIdx.x;
    const int row0 = blockIdx.x * MROWS;

    // stage W1 (2048 float4)
    {
        const float4* w4 = (const float4*)W1;
        float4* s4 = (float4*)Ws;
        for (int i = t; i < 2048; i += 256) s4[i] = w4[i];
    }
    if (t < 128) b1s[t] = b1[t];
    // stage x transposed: 512 float4 global loads
#pragma unroll
    for (int c = 0; c < 2; ++c) {
        int lin = t + c * 256;            // 0..511
        int r = lin >> 4;                 // 0..31
        int k4 = lin & 15;                // 0..15
        float4 v = *(const float4*)(A + (size_t)(row0 + r) * 64 + k4 * 4);
        xs[(k4 * 4 + 0) * 36 + r] = v.x;
        xs[(k4 * 4 + 1) * 36 + r] = v.y;
        xs[(k4 * 4 + 2) * 36 + r] = v.z;
        xs[(k4 * 4 + 3) * 36 + r] = v.w;
    }
    __syncthreads();

    // ---- phase 1: h = relu(x*W1 + b1), 4 rows x 4 cols per thread ----
    {
        const int rg = t >> 5, cg = t & 31;
        const int r0 = rg * 4, c0 = cg * 4;
        float4 bv = *(const float4*)&b1s[c0];
        float4 acc0 = bv, acc1 = bv, acc2 = bv, acc3 = bv;
#pragma unroll 8
        for (int k = 0; k < 64; ++k) {
            float4 w = *(const float4*)&Ws[k * 128 + c0];
            float4 a = *(const float4*)&xs[k * 36 + r0];
            acc0.x = fmaf(a.x, w.x, acc0.x); acc0.y = fmaf(a.x, w.y, acc0.y);
            acc0.z = fmaf(a.x, w.z, acc0.z); acc0.w = fmaf(a.x, w.w, acc0.w);
            acc1.x = fmaf(a.y, w.x, acc1.x); acc1.y = fmaf(a.y, w.y, acc1.y);
            acc1.z = fmaf(a.y, w.z, acc1.z); acc1.w = fmaf(a.y, w.w, acc1.w);
            acc2.x = fmaf(a.z, w.x, acc2.x); acc2.y = fmaf(a.z, w.y, acc2.y);
            acc2.z = fmaf(a.z, w.z, acc2.z); acc2.w = fmaf(a.z, w.w, acc2.w);
            acc3.x = fmaf(a.w, w.x, acc3.x); acc3.y = fmaf(a.w, w.y, acc3.y);
            acc3.z = fmaf(a.w, w.z, acc3.z); acc3.w = fmaf(a.w, w.w, acc3.w);
        }
        float4 h;
        h.x = fmaxf(acc0.x, 0.f); h.y = fmaxf(acc0.y, 0.f); h.z = fmaxf(acc0.z, 0.f); h.w = fmaxf(acc0.w, 0.f);
        *(float4*)&hs[(r0 + 0) * 132 + c0] = h;
        h.x = fmaxf(acc1.x, 0.f); h.y = fmaxf(acc1.y, 0.f); h.z = fmaxf(acc1.z, 0.f); h.w = fmaxf(acc1.w, 0.f);
        *(float4*)&hs[(r0 + 1) * 132 + c0] = h;
        h.x = fmaxf(acc2.x, 0.f); h.y = fmaxf(acc2.y, 0.f); h.z = fmaxf(acc2.z, 0.f); h.w = fmaxf(acc2.w, 0.f);
        *(float4*)&hs[(r0 + 2) * 132 + c0] = h;
        h.x = fmaxf(acc3.x, 0.f); h.y = fmaxf(acc3.y, 0.f); h.z = fmaxf(acc3.z, 0.f); h.w = fmaxf(acc3.w, 0.f);
        *(float4*)&hs[(r0 + 3) * 132 + c0] = h;
    }
    __syncthreads();

    // stage W2 into the same LDS buffer
    {
        const float4* w4 = (const float4*)W2;
        float4* s4 = (float4*)Ws;
        for (int i = t; i < 2048; i += 256) s4[i] = w4[i];
    }
    __syncthreads();

    // ---- phase 2: z = h*W2, 2 rows x 4 cols per thread ----
    {
        const int rg = t >> 4, cg = t & 15;
        const int r0 = rg * 2, c0 = cg * 4;
        float4 acc0 = make_float4(0.f, 0.f, 0.f, 0.f);
        float4 acc1 = make_float4(0.f, 0.f, 0.f, 0.f);
#pragma unroll 8
        for (int k = 0; k < 128; ++k) {
            float4 w = *(const float4*)&Ws[k * 64 + c0];
            float h0 = hs[(r0 + 0) * 132 + k];
            float h1 = hs[(r0 + 1) * 132 + k];
            acc0.x = fmaf(h0, w.x, acc0.x); acc0.y = fmaf(h0, w.y, acc0.y);
            acc0.z = fmaf(h0, w.z, acc0.z); acc0.w = fmaf(h0, w.w, acc0.w);
            acc1.x = fmaf(h1, w.x, acc1.x); acc1.y = fmaf(h1, w.y, acc1.y);
            acc1.z = fmaf(h1, w.z, acc1.z); acc1.w = fmaf(h1, w.w, acc1.w);
        }
        *(float4*)(A + (size_t)(row0 + r0 + 0) * 64 + c0) = acc0;
        *(float4*)(A + (size_t)(row0 + r0 + 1) * 64 + c0) = acc1;
    }
}

extern "C" void kernel_launch(void* const* d_in, const int* in_sizes, int n_in,
                              void* d_out, int out_size, void* d_ws, size_t ws_size,
                              hipStream_t stream) {
    const float* x  = (const float*)d_in[0];
    const float* W1 = (const float*)d_in[1];
    const float* b1 = (const float*)d_in[2];
    const float* W2 = (const float*)d_in[3];
    const float* b2 = (const float*)d_in[4];
    const int* src  = (const int*)d_in[5];
    const int* dst  = (const int*)d_in[6];
    float* out = (float*)d_out;

    const int nfeat = N_NODES * 64;
    const int nfeat4 = nfeat / 4;

    // workspace layout
    char* ws = (char*)d_ws;
    float* A    = (float*)ws;                    ws += (size_t)nfeat * 4;          // 25.6 MB
    int* deg    = (int*)ws;                      ws += (size_t)N_NODES * 4;
    int* off    = (int*)ws;                      ws += (size_t)(N_NODES + 1) * 4;
    int* cursor = (int*)ws;                      ws += (size_t)N_NODES * 4;
    int* es     = (int*)ws;                      ws += (size_t)N_EDGES * 4;        // 6.4 MB
    size_t need = (size_t)(ws - (char*)d_ws);

    if (ws_size >= need) {
        // ---- CSR build ----
        k_zero_i<<<(N_NODES + 255) / 256, 256, 0, stream>>>(deg, N_NODES);
        k_hist<<<(N_EDGES + 255) / 256, 256, 0, stream>>>(dst, deg);
        k_scan<<<1, 1024, 0, stream>>>(deg, off);
        k_zero_i<<<(N_NODES + 255) / 256, 256, 0, stream>>>(cursor, N_NODES);
        k_fill<<<(N_EDGES + 255) / 256, 256, 0, stream>>>(src, dst, off, cursor, es);

        // ---- layer 1 aggregate: A = segsum(x) ----
        k_gather<<<(N_NODES + 3) / 4, 256, 0, stream>>>(x, es, off, nullptr, A);
        // ---- MLP in place: A = relu(A*W1+b1)*W2 ----
        k_mlp<<<N_NODES / MROWS, 256, 0, stream>>>(A, W1, b1, W2);
        // ---- layer 2 aggregate + bias: out = b2 + segsum(A) ----
        k_gather<<<(N_NODES + 3) / 4, 256, 0, stream>>>(A, es, off, b2, out);
    } else {
        // fallback: atomic scatter path
        k_zero_f4<<<(nfeat4 + 255) / 256, 256, 0, stream>>>((float4*)A, nfeat4);
        int threads = N_EDGES * 16;
        k_scatter64<<<(threads + 255) / 256, 256, 0, stream>>>(x, src, dst, A);
        k_mlp<<<N_NODES / MROWS, 256, 0, stream>>>(A, W1, b1, W2);
        k_init_bias<<<(nfeat + 255) / 256, 256, 0, stream>>>(out, b2, nfeat);
        k_scatter64<<<(threads + 255) / 256, 256, 0, stream>>>(A, src, dst, out);
    }
}

// Round 4
// 333.462 us; speedup vs baseline: 8.9023x; 1.5896x over previous
//
#include <hip/hip_runtime.h>

#define N_NODES 100000
#define N_EDGES 1600000
#define IN_F 64
#define HID 128
#define N_CLS 64

#define SCAN_B 1024
#define NB ((N_NODES + SCAN_B - 1) / SCAN_B)   // 98

// ================= generic helpers =================
__global__ void k_zero_f4(float4* __restrict__ p, int n4) {
    int i = blockIdx.x * blockDim.x + threadIdx.x;
    if (i < n4) p[i] = make_float4(0.f, 0.f, 0.f, 0.f);
}
__global__ void k_zero_i(int* __restrict__ p, int n) {
    int i = blockIdx.x * blockDim.x + threadIdx.x;
    if (i < n) p[i] = 0;
}
__global__ void k_init_bias(float* __restrict__ out, const float* __restrict__ b2, int n) {
    int i = blockIdx.x * blockDim.x + threadIdx.x;
    if (i < n) out[i] = b2[i & 63];
}

// ================= CSR build =================
__global__ void k_hist(const int* __restrict__ dst, int* __restrict__ deg) {
    int e = blockIdx.x * blockDim.x + threadIdx.x;
    if (e < N_EDGES) atomicAdd(&deg[dst[e]], 1);
}

// ---- two-level scan: per-block exclusive scan + block totals ----
__global__ __launch_bounds__(SCAN_B) void k_scan1(const int* __restrict__ deg,
                                                  int* __restrict__ off,
                                                  int* __restrict__ blockTot) {
    __shared__ int buf[2][SCAN_B];
    const int t = threadIdx.x;
    const int gid = blockIdx.x * SCAN_B + t;
    int v = (gid < N_NODES) ? deg[gid] : 0;
    buf[0][t] = v;
    __syncthreads();
    int cur = 0;
    for (int d = 1; d < SCAN_B; d <<= 1) {
        int x = buf[cur][t];
        if (t >= d) x += buf[cur][t - d];
        buf[cur ^ 1][t] = x;
        __syncthreads();
        cur ^= 1;
    }
    if (gid < N_NODES) off[gid] = buf[cur][t] - v;     // exclusive within block
    if (t == SCAN_B - 1) blockTot[blockIdx.x] = buf[cur][t];
}

// ---- scan the (98) block totals, single small block ----
__global__ __launch_bounds__(128) void k_scan2(const int* __restrict__ blockTot,
                                               int* __restrict__ blockOff) {
    __shared__ int buf[2][128];
    const int t = threadIdx.x;
    int v = (t < NB) ? blockTot[t] : 0;
    buf[0][t] = v;
    __syncthreads();
    int cur = 0;
    for (int d = 1; d < 128; d <<= 1) {
        int x = buf[cur][t];
        if (t >= d) x += buf[cur][t - d];
        buf[cur ^ 1][t] = x;
        __syncthreads();
        cur ^= 1;
    }
    if (t < NB) blockOff[t] = buf[cur][t] - v;         // exclusive
}

// ---- add block offsets; set sentinel ----
__global__ void k_scan3(int* __restrict__ off, const int* __restrict__ blockOff) {
    int i = blockIdx.x * blockDim.x + threadIdx.x;
    if (i < N_NODES) off[i] += blockOff[i >> 10];
    else if (i == N_NODES) off[N_NODES] = N_EDGES;
}

__global__ void k_fill(const int* __restrict__ src, const int* __restrict__ dst,
                       const int* __restrict__ off, int* __restrict__ cursor,
                       int* __restrict__ es) {
    int e = blockIdx.x * blockDim.x + threadIdx.x;
    if (e >= N_EDGES) return;
    int d = dst[e];
    int pos = atomicAdd(&cursor[d], 1);
    es[off[d] + pos] = src[e];
}

// ================= gather aggregation: one wave per node =================
__global__ __launch_bounds__(256) void k_gather(const float* __restrict__ feat,
                                                const int* __restrict__ es,
                                                const int* __restrict__ off,
                                                const float* __restrict__ bias,
                                                float* __restrict__ out) {
    const int wave = threadIdx.x >> 6;
    const int lane = threadIdx.x & 63;
    const int n = blockIdx.x * 4 + wave;
    if (n >= N_NODES) return;
    const int beg = off[n], end = off[n + 1];
    float acc = bias ? bias[lane] : 0.f;
    for (int base = beg; base < end; base += 64) {
        int m = end - base; if (m > 64) m = 64;
        int id = (lane < m) ? es[base + lane] : 0;
        int k = 0;
        for (; k + 4 <= m; k += 4) {
            int s0 = __shfl(id, k), s1 = __shfl(id, k + 1);
            int s2 = __shfl(id, k + 2), s3 = __shfl(id, k + 3);
            float v0 = feat[(size_t)s0 * 64 + lane];
            float v1 = feat[(size_t)s1 * 64 + lane];
            float v2 = feat[(size_t)s2 * 64 + lane];
            float v3 = feat[(size_t)s3 * 64 + lane];
            acc += (v0 + v1) + (v2 + v3);
        }
        for (; k < m; ++k) {
            int s = __shfl(id, k);
            acc += feat[(size_t)s * 64 + lane];
        }
    }
    out[(size_t)n * 64 + lane] = acc;
}

// ================= fallback atomic scatter (if ws too small) =================
__global__ void k_scatter64(const float* __restrict__ feat,
                            const int* __restrict__ src,
                            const int* __restrict__ dst,
                            float* __restrict__ out) {
    int i = blockIdx.x * blockDim.x + threadIdx.x;
    int e = i >> 4;
    if (e >= N_EDGES) return;
    int j = (i & 15) << 2;
    int s = src[e];
    int d = dst[e];
    float4 v = *reinterpret_cast<const float4*>(feat + (size_t)s * 64 + j);
    float* o = out + (size_t)d * 64 + j;
    atomicAdd(o + 0, v.x);
    atomicAdd(o + 1, v.y);
    atomicAdd(o + 2, v.z);
    atomicAdd(o + 3, v.w);
}

// ================= fused MLP: Z = relu(A*W1 + b1) * W2, in-place, register-tiled =================
#define MROWS 32
__global__ __launch_bounds__(256, 2) void k_mlp(float* __restrict__ A,
                                                const float* __restrict__ W1,
                                                const float* __restrict__ b1,
                                                const float* __restrict__ W2) {
    __shared__ float Ws[64 * 128];      // 32 KB: holds W1, then reused for W2
    __shared__ float xs[64 * 36];       // x transposed [k][row], padded stride 36
    __shared__ float hs[32 * 132];      // h row-major, padded stride 132
    __shared__ float b1s[128];
    const int t = threadIdx.x;
    const int row0 = blockIdx.x * MROWS;

    // stage W1 (2048 float4)
    {
        const float4* w4 = (const float4*)W1;
        float4* s4 = (float4*)Ws;
        for (int i = t; i < 2048; i += 256) s4[i] = w4[i];
    }
    if (t < 128) b1s[t] = b1[t];
    // stage x transposed: 512 float4 global loads
#pragma unroll
    for (int c = 0; c < 2; ++c) {
        int lin = t + c * 256;            // 0..511
        int r = lin >> 4;                 // 0..31
        int k4 = lin & 15;                // 0..15
        float4 v = *(const float4*)(A + (size_t)(row0 + r) * 64 + k4 * 4);
        xs[(k4 * 4 + 0) * 36 + r] = v.x;
        xs[(k4 * 4 + 1) * 36 + r] = v.y;
        xs[(k4 * 4 + 2) * 36 + r] = v.z;
        xs[(k4 * 4 + 3) * 36 + r] = v.w;
    }
    __syncthreads();

    // ---- phase 1: h = relu(x*W1 + b1), 4 rows x 4 cols per thread ----
    {
        const int rg = t >> 5, cg = t & 31;
        const int r0 = rg * 4, c0 = cg * 4;
        float4 bv = *(const float4*)&b1s[c0];
        float4 acc0 = bv, acc1 = bv, acc2 = bv, acc3 = bv;
#pragma unroll 8
        for (int k = 0; k < 64; ++k) {
            float4 w = *(const float4*)&Ws[k * 128 + c0];
            float4 a = *(const float4*)&xs[k * 36 + r0];
            acc0.x = fmaf(a.x, w.x, acc0.x); acc0.y = fmaf(a.x, w.y, acc0.y);
            acc0.z = fmaf(a.x, w.z, acc0.z); acc0.w = fmaf(a.x, w.w, acc0.w);
            acc1.x = fmaf(a.y, w.x, acc1.x); acc1.y = fmaf(a.y, w.y, acc1.y);
            acc1.z = fmaf(a.y, w.z, acc1.z); acc1.w = fmaf(a.y, w.w, acc1.w);
            acc2.x = fmaf(a.z, w.x, acc2.x); acc2.y = fmaf(a.z, w.y, acc2.y);
            acc2.z = fmaf(a.z, w.z, acc2.z); acc2.w = fmaf(a.z, w.w, acc2.w);
            acc3.x = fmaf(a.w, w.x, acc3.x); acc3.y = fmaf(a.w, w.y, acc3.y);
            acc3.z = fmaf(a.w, w.z, acc3.z); acc3.w = fmaf(a.w, w.w, acc3.w);
        }
        float4 h;
        h.x = fmaxf(acc0.x, 0.f); h.y = fmaxf(acc0.y, 0.f); h.z = fmaxf(acc0.z, 0.f); h.w = fmaxf(acc0.w, 0.f);
        *(float4*)&hs[(r0 + 0) * 132 + c0] = h;
        h.x = fmaxf(acc1.x, 0.f); h.y = fmaxf(acc1.y, 0.f); h.z = fmaxf(acc1.z, 0.f); h.w = fmaxf(acc1.w, 0.f);
        *(float4*)&hs[(r0 + 1) * 132 + c0] = h;
        h.x = fmaxf(acc2.x, 0.f); h.y = fmaxf(acc2.y, 0.f); h.z = fmaxf(acc2.z, 0.f); h.w = fmaxf(acc2.w, 0.f);
        *(float4*)&hs[(r0 + 2) * 132 + c0] = h;
        h.x = fmaxf(acc3.x, 0.f); h.y = fmaxf(acc3.y, 0.f); h.z = fmaxf(acc3.z, 0.f); h.w = fmaxf(acc3.w, 0.f);
        *(float4*)&hs[(r0 + 3) * 132 + c0] = h;
    }
    __syncthreads();

    // stage W2 into the same LDS buffer
    {
        const float4* w4 = (const float4*)W2;
        float4* s4 = (float4*)Ws;
        for (int i = t; i < 2048; i += 256) s4[i] = w4[i];
    }
    __syncthreads();

    // ---- phase 2: z = h*W2, 2 rows x 4 cols per thread ----
    {
        const int rg = t >> 4, cg = t & 15;
        const int r0 = rg * 2, c0 = cg * 4;
        float4 acc0 = make_float4(0.f, 0.f, 0.f, 0.f);
        float4 acc1 = make_float4(0.f, 0.f, 0.f, 0.f);
#pragma unroll 8
        for (int k = 0; k < 128; ++k) {
            float4 w = *(const float4*)&Ws[k * 64 + c0];
            float h0 = hs[(r0 + 0) * 132 + k];
            float h1 = hs[(r0 + 1) * 132 + k];
            acc0.x = fmaf(h0, w.x, acc0.x); acc0.y = fmaf(h0, w.y, acc0.y);
            acc0.z = fmaf(h0, w.z, acc0.z); acc0.w = fmaf(h0, w.w, acc0.w);
            acc1.x = fmaf(h1, w.x, acc1.x); acc1.y = fmaf(h1, w.y, acc1.y);
            acc1.z = fmaf(h1, w.z, acc1.z); acc1.w = fmaf(h1, w.w, acc1.w);
        }
        *(float4*)(A + (size_t)(row0 + r0 + 0) * 64 + c0) = acc0;
        *(float4*)(A + (size_t)(row0 + r0 + 1) * 64 + c0) = acc1;
    }
}

extern "C" void kernel_launch(void* const* d_in, const int* in_sizes, int n_in,
                              void* d_out, int out_size, void* d_ws, size_t ws_size,
                              hipStream_t stream) {
    const float* x  = (const float*)d_in[0];
    const float* W1 = (const float*)d_in[1];
    const float* b1 = (const float*)d_in[2];
    const float* W2 = (const float*)d_in[3];
    const float* b2 = (const float*)d_in[4];
    const int* src  = (const int*)d_in[5];
    const int* dst  = (const int*)d_in[6];
    float* out = (float*)d_out;

    const int nfeat = N_NODES * 64;
    const int nfeat4 = nfeat / 4;

    // workspace layout
    char* ws = (char*)d_ws;
    float* A    = (float*)ws;                    ws += (size_t)nfeat * 4;          // 25.6 MB
    int* deg    = (int*)ws;                      ws += (size_t)N_NODES * 4;
    int* cursor = (int*)ws;                      ws += (size_t)N_NODES * 4;        // adjacent to deg: one zero pass
    int* off    = (int*)ws;                      ws += (size_t)(N_NODES + 1) * 4;
    int* es     = (int*)ws;                      ws += (size_t)N_EDGES * 4;        // 6.4 MB
    int* blockTot = (int*)ws;                    ws += (size_t)NB * 4;
    int* blockOff = (int*)ws;                    ws += (size_t)NB * 4;
    size_t need = (size_t)(ws - (char*)d_ws);

    if (ws_size >= need) {
        // ---- CSR build ----
        k_zero_i<<<(2 * N_NODES + 255) / 256, 256, 0, stream>>>(deg, 2 * N_NODES);  // deg + cursor
        k_hist<<<(N_EDGES + 255) / 256, 256, 0, stream>>>(dst, deg);
        k_scan1<<<NB, SCAN_B, 0, stream>>>(deg, off, blockTot);
        k_scan2<<<1, 128, 0, stream>>>(blockTot, blockOff);
        k_scan3<<<(N_NODES + 1 + 1023) / 1024, 1024, 0, stream>>>(off, blockOff);
        k_fill<<<(N_EDGES + 255) / 256, 256, 0, stream>>>(src, dst, off, cursor, es);

        // ---- layer 1 aggregate: A = segsum(x) ----
        k_gather<<<(N_NODES + 3) / 4, 256, 0, stream>>>(x, es, off, nullptr, A);
        // ---- MLP in place: A = relu(A*W1+b1)*W2 ----
        k_mlp<<<N_NODES / MROWS, 256, 0, stream>>>(A, W1, b1, W2);
        // ---- layer 2 aggregate + bias: out = b2 + segsum(A) ----
        k_gather<<<(N_NODES + 3) / 4, 256, 0, stream>>>(A, es, off, b2, out);
    } else {
        // fallback: atomic scatter path
        k_zero_f4<<<(nfeat4 + 255) / 256, 256, 0, stream>>>((float4*)A, nfeat4);
        int threads = N_EDGES * 16;
        k_scatter64<<<(threads + 255) / 256, 256, 0, stream>>>(x, src, dst, A);
        k_mlp<<<N_NODES / MROWS, 256, 0, stream>>>(A, W1, b1, W2);
        k_init_bias<<<(nfeat + 255) / 256, 256, 0, stream>>>(out, b2, nfeat);
        k_scatter64<<<(threads + 255) / 256, 256, 0, stream>>>(A, src, dst, out);
    }
}